// Round 1
// baseline (411.524 us; speedup 1.0000x reference)
//
#include <hip/hip_runtime.h>

#define T_TOKENS 2048
#define N_EXPERTS 8
#define ROWS (T_TOKENS * 2)      // T * TOPK
#define I_DIM 2048
#define H_DIM 1024

#define M_TILE 128
#define N_TILE 128
#define BK 32
#define KSPLIT 2
#define KCHUNK (I_DIM / KSPLIT)  // 1024

typedef __bf16 bf16x8 __attribute__((ext_vector_type(8)));
typedef __bf16 bf16x4 __attribute__((ext_vector_type(4)));
typedef float f32x4 __attribute__((ext_vector_type(4)));

__global__ void zero_cnt_kernel(int* cnt) {
    if (threadIdx.x < N_EXPERTS) cnt[threadIdx.x] = 0;
}

// One thread per token: softmax over 8 logits, top-2 (jax tie-break: lower index
// first via strict '>'), store weights by flat row id, append rows to per-expert lists.
__global__ void routing_kernel(const float* __restrict__ logits,
                               float* __restrict__ topk_w,
                               int* __restrict__ cnt,
                               int* __restrict__ rowlist) {
    int t = blockIdx.x * blockDim.x + threadIdx.x;
    if (t >= T_TOKENS) return;
    float l[8];
#pragma unroll
    for (int e = 0; e < 8; ++e) l[e] = logits[t * 8 + e];
    float mx = l[0];
#pragma unroll
    for (int e = 1; e < 8; ++e) mx = fmaxf(mx, l[e]);
    float s = 0.f;
#pragma unroll
    for (int e = 0; e < 8; ++e) { l[e] = expf(l[e] - mx); s += l[e]; }
    float inv = 1.f / s;
    float v0 = -1.f, v1 = -1.f; int i0 = 0, i1 = 0;
#pragma unroll
    for (int e = 0; e < 8; ++e) {
        float p = l[e] * inv;
        if (p > v0)      { v1 = v0; i1 = i0; v0 = p; i0 = e; }
        else if (p > v1) { v1 = p; i1 = e; }
    }
    topk_w[2 * t]     = v0;
    topk_w[2 * t + 1] = v1;
    int p0 = atomicAdd(&cnt[i0], 1); rowlist[i0 * ROWS + p0] = 2 * t;
    int p1 = atomicAdd(&cnt[i1], 1); rowlist[i1 * ROWS + p1] = 2 * t + 1;
}

// Grouped expert GEMM: scratch[khalf][row][H] = x[row] @ W[e] (partial over K-half),
// rows gathered via per-expert lists. bf16 MFMA 16x16x32, fragment-ordered LDS.
__global__ __launch_bounds__(256, 2) void gemm_kernel(
    const float* __restrict__ x, const float* __restrict__ w,
    const int* __restrict__ cnt, const int* __restrict__ rowlist,
    float* __restrict__ scratch) {
    const int e = blockIdx.z;
    const int cnt_e = cnt[e];
    const int m0 = blockIdx.x * M_TILE;
    if (m0 >= cnt_e) return;
    const int ntile = blockIdx.y & 7;
    const int khalf = blockIdx.y >> 3;
    const int n0 = ntile * N_TILE;
    const int tid = threadIdx.x;
    const int lane = tid & 63;
    const int wave = tid >> 6;
    const int wm = wave & 1, wn = wave >> 1;

    // fragment-ordered: chunk(m,k) = (m>>4)*64 + (k>>3)*16 + (m&15); elem = chunk*8 + (k&7)
    __shared__ __bf16 As[M_TILE * BK];
    __shared__ __bf16 Bs[N_TILE * BK];

    const int* rl = rowlist + e * ROWS;

    // A staging: 4 passes of 32 rows; thread -> row p*32 + tid/8, k = (tid%8)*4 (float4)
    const int am_k = (tid & 7) * 4;
    const float* aptr[4];
#pragma unroll
    for (int p = 0; p < 4; ++p) {
        int gm = m0 + p * 32 + (tid >> 3);
        int gmc = gm < cnt_e ? gm : cnt_e - 1;   // clamp: garbage rows discarded in epilogue
        aptr[p] = x + rl[gmc] * I_DIM + am_k;
    }
    // B staging: thread -> col n = tid&127, k-quad = (tid>>7)*4; loads are n-coalesced
    const int bn = tid & 127;
    const int bkq = (tid >> 7) * 4;
    const float* bptr = w + (size_t)e * (I_DIM * H_DIM) + n0 + bn;

    f32x4 acc[4][4];
#pragma unroll
    for (int mt = 0; mt < 4; ++mt)
#pragma unroll
        for (int nt = 0; nt < 4; ++nt)
            acc[mt][nt] = (f32x4){0.f, 0.f, 0.f, 0.f};

    const int k_begin = khalf * KCHUNK;
    for (int k0 = k_begin; k0 < k_begin + KCHUNK; k0 += BK) {
        __syncthreads();
        // stage A (fp32 -> bf16)
#pragma unroll
        for (int p = 0; p < 4; ++p) {
            f32x4 v = *(const f32x4*)(aptr[p] + k0);
            int m = p * 32 + (tid >> 3);
            bf16x4 b = { (__bf16)v.x, (__bf16)v.y, (__bf16)v.z, (__bf16)v.w };
            int chunk = (m >> 4) * 64 + (am_k >> 3) * 16 + (m & 15);
            *(bf16x4*)&As[chunk * 8 + (am_k & 7)] = b;
        }
        // stage B (k-strided, n-coalesced)
#pragma unroll
        for (int kk = 0; kk < 32; kk += 8) {
            int k = kk + bkq;
            const float* bp = bptr + (size_t)(k0 + k) * H_DIM;
            float f0 = bp[0];
            float f1 = bp[H_DIM];
            float f2 = bp[2 * H_DIM];
            float f3 = bp[3 * H_DIM];
            bf16x4 b = { (__bf16)f0, (__bf16)f1, (__bf16)f2, (__bf16)f3 };
            int chunk = (bn >> 4) * 64 + (k >> 3) * 16 + (bn & 15);
            *(bf16x4*)&Bs[chunk * 8 + (k & 7)] = b;
        }
        __syncthreads();
        bf16x8 af[4], bfr[4];
#pragma unroll
        for (int mt = 0; mt < 4; ++mt)
            af[mt] = *(const bf16x8*)&As[((wm * 4 + mt) * 64 + lane) * 8];
#pragma unroll
        for (int nt = 0; nt < 4; ++nt)
            bfr[nt] = *(const bf16x8*)&Bs[((wn * 4 + nt) * 64 + lane) * 8];
#pragma unroll
        for (int mt = 0; mt < 4; ++mt)
#pragma unroll
            for (int nt = 0; nt < 4; ++nt)
                acc[mt][nt] = __builtin_amdgcn_mfma_f32_16x16x32_bf16(
                    af[mt], bfr[nt], acc[mt][nt], 0, 0, 0);
    }

    // epilogue: C/D layout col=lane&15, row=(lane>>4)*4+reg
    float* sbase = scratch + (size_t)khalf * ROWS * H_DIM;
    const int lq = lane >> 4, ln = lane & 15;
#pragma unroll
    for (int mt = 0; mt < 4; ++mt) {
#pragma unroll
        for (int j = 0; j < 4; ++j) {
            int gm = m0 + wm * 64 + mt * 16 + lq * 4 + j;
            if (gm < cnt_e) {
                int row = rl[gm];
                float* orow = sbase + (size_t)row * H_DIM + n0 + ln;
#pragma unroll
                for (int nt = 0; nt < 4; ++nt)
                    orow[(wn * 4 + nt) * 16] = acc[mt][nt][j];
            }
        }
    }
}

// out[t] = w0*(s0[2t]+s1[2t]) + w1*(s0[2t+1]+s1[2t+1])
__global__ void reduce_kernel(const float* __restrict__ scratch,
                              const float* __restrict__ topk_w,
                              float* __restrict__ out) {
    int idx = blockIdx.x * blockDim.x + threadIdx.x;   // over T*H/4
    int t = idx >> 8;          // H/4 = 256 float4 per token
    int hq = idx & 255;
    float w0 = topk_w[2 * t];
    float w1 = topk_w[2 * t + 1];
    const f32x4* s = (const f32x4*)scratch;
    f32x4 a0 = s[(size_t)(2 * t) * 256 + hq];
    f32x4 a1 = s[(size_t)(2 * t + 1) * 256 + hq];
    f32x4 b0 = s[(size_t)ROWS * 256 + (size_t)(2 * t) * 256 + hq];
    f32x4 b1 = s[(size_t)ROWS * 256 + (size_t)(2 * t + 1) * 256 + hq];
    f32x4 r = (a0 + b0) * w0 + (a1 + b1) * w1;
    ((f32x4*)out)[idx] = r;
}

extern "C" void kernel_launch(void* const* d_in, const int* in_sizes, int n_in,
                              void* d_out, int out_size, void* d_ws, size_t ws_size,
                              hipStream_t stream) {
    const float* x      = (const float*)d_in[0];  // [ROWS, I_DIM] fp32
    const float* w      = (const float*)d_in[1];  // [E, I_DIM, H_DIM] fp32
    const float* logits = (const float*)d_in[2];  // [T, E] fp32
    float* out = (float*)d_out;                   // [T, H_DIM] fp32

    char* ws = (char*)d_ws;
    float* topk_w  = (float*)ws;                                  // 4096 f32
    int*   cnt     = (int*)(ws + 16384);                          // 8 int (padded to 128B)
    int*   rowlist = (int*)(ws + 16384 + 128);                    // 8*4096 int
    float* scratch = (float*)(ws + 16384 + 128 + 131072);         // 2*4096*1024 f32 (32 MB)

    zero_cnt_kernel<<<1, 64, 0, stream>>>(cnt);
    routing_kernel<<<T_TOKENS / 256, 256, 0, stream>>>(logits, topk_w, cnt, rowlist);
    gemm_kernel<<<dim3(ROWS / M_TILE, (H_DIM / N_TILE) * KSPLIT, N_EXPERTS), 256, 0, stream>>>(
        x, w, cnt, rowlist, scratch);
    reduce_kernel<<<(T_TOKENS * H_DIM / 4) / 256, 256, 0, stream>>>(scratch, topk_w, out);
}

// Round 2
// 322.027 us; speedup vs baseline: 1.2779x; 1.2779x over previous
//
#include <hip/hip_runtime.h>

#define T_TOKENS 2048
#define N_EXPERTS 8
#define ROWS (T_TOKENS * 2)      // T * TOPK
#define I_DIM 2048
#define H_DIM 1024

#define M_TILE 64
#define N_TILE 128
#define BK 32
#define KSPLIT 2
#define KCHUNK (I_DIM / KSPLIT)  // 1024

typedef __bf16 bf16x8 __attribute__((ext_vector_type(8)));
typedef __bf16 bf16x4 __attribute__((ext_vector_type(4)));
typedef float f32x4 __attribute__((ext_vector_type(4)));

// One thread per token: softmax over 8 logits, top-2 (strict '>' keeps lower index
// first on ties, matching jax.lax.top_k), append rows to per-expert lists.
__global__ void routing_kernel(const float* __restrict__ logits,
                               float* __restrict__ topk_w,
                               int* __restrict__ cnt,
                               int* __restrict__ rowlist) {
    int t = blockIdx.x * blockDim.x + threadIdx.x;
    if (t >= T_TOKENS) return;
    float l[8];
#pragma unroll
    for (int e = 0; e < 8; ++e) l[e] = logits[t * 8 + e];
    float mx = l[0];
#pragma unroll
    for (int e = 1; e < 8; ++e) mx = fmaxf(mx, l[e]);
    float s = 0.f;
#pragma unroll
    for (int e = 0; e < 8; ++e) { l[e] = expf(l[e] - mx); s += l[e]; }
    float inv = 1.f / s;
    float v0 = -1.f, v1 = -1.f; int i0 = 0, i1 = 0;
#pragma unroll
    for (int e = 0; e < 8; ++e) {
        float p = l[e] * inv;
        if (p > v0)      { v1 = v0; i1 = i0; v0 = p; i0 = e; }
        else if (p > v1) { v1 = p; i1 = e; }
    }
    topk_w[2 * t]     = v0;
    topk_w[2 * t + 1] = v1;
    int p0 = atomicAdd(&cnt[i0], 1); rowlist[i0 * ROWS + p0] = 2 * t;
    int p1 = atomicAdd(&cnt[i1], 1); rowlist[i1 * ROWS + p1] = 2 * t + 1;
}

// Grouped expert GEMM, 64x128 tile, bf16 MFMA 16x16x32, fragment-ordered LDS,
// register-prefetch software pipeline (loads for iter k+1 issued during iter k's
// MFMA phase -> single vmcnt wait per iter, overlapped with compute).
__global__ __launch_bounds__(256, 4) void gemm_kernel(
    const float* __restrict__ x, const float* __restrict__ w,
    const int* __restrict__ cnt, const int* __restrict__ rowlist,
    float* __restrict__ scratch) {
    const int e = blockIdx.z;
    const int cnt_e = cnt[e];
    const int m0 = blockIdx.x * M_TILE;
    if (m0 >= cnt_e) return;
    const int ntile = blockIdx.y & 7;
    const int khalf = blockIdx.y >> 3;
    const int n0 = ntile * N_TILE;
    const int tid = threadIdx.x;
    const int lane = tid & 63;
    const int wave = tid >> 6;
    const int wm = wave & 1, wn = wave >> 1;

    // fragment-ordered: chunk(m,k) = (m>>4)*64 + (k>>3)*16 + (m&15); elem = chunk*8 + (k&7)
    __shared__ __bf16 As[M_TILE * BK];   // 4 KB
    __shared__ __bf16 Bs[N_TILE * BK];   // 8 KB

    const int* rl = rowlist + e * ROWS;

    // A: thread -> row tid>>2 (64 rows), k-offset (tid&3)*8; one b128 LDS store
    const int arow = tid >> 2;
    const int ak = (tid & 3) * 8;
    int gmA = m0 + arow;
    int gmc = gmA < cnt_e ? gmA : cnt_e - 1;   // clamped garbage rows dropped in epilogue
    const float* aptr = x + (size_t)rl[gmc] * I_DIM + ak;
    __bf16* as_ptr = &As[((arow >> 4) * 64 + (ak >> 3) * 16 + (arow & 15)) * 8];

    // B: thread -> n quad (tid&31)*4, k quad (tid>>5)*4; 4 float4 loads, 4 b64 stores
    const int bn = (tid & 31) * 4;
    const int bkq = (tid >> 5) * 4;
    const float* bptr = w + (size_t)e * (I_DIM * H_DIM) + (size_t)bkq * H_DIM + n0 + bn;
    __bf16* bs_ptr[4];
#pragma unroll
    for (int j = 0; j < 4; ++j) {
        int n = bn + j;
        bs_ptr[j] = &Bs[(((n >> 4) * 64 + (bkq >> 3) * 16 + (n & 15)) * 8) + (bkq & 7)];
    }

    f32x4 acc[2][4];
#pragma unroll
    for (int mt = 0; mt < 2; ++mt)
#pragma unroll
        for (int nt = 0; nt < 4; ++nt)
            acc[mt][nt] = (f32x4){0.f, 0.f, 0.f, 0.f};

    const int k_begin = khalf * KCHUNK;
    const int k_end = k_begin + KCHUNK;

    // prologue loads
    f32x4 va0 = *(const f32x4*)(aptr + k_begin);
    f32x4 va1 = *(const f32x4*)(aptr + k_begin + 4);
    f32x4 vb[4];
#pragma unroll
    for (int i = 0; i < 4; ++i)
        vb[i] = *(const f32x4*)(bptr + (size_t)(k_begin + i) * H_DIM);

    for (int k0 = k_begin; k0 < k_end; k0 += BK) {
        // convert & store current registers to LDS
        bf16x8 a8 = { (__bf16)va0.x, (__bf16)va0.y, (__bf16)va0.z, (__bf16)va0.w,
                      (__bf16)va1.x, (__bf16)va1.y, (__bf16)va1.z, (__bf16)va1.w };
        *(bf16x8*)as_ptr = a8;
#pragma unroll
        for (int j = 0; j < 4; ++j) {
            bf16x4 b4 = { (__bf16)vb[0][j], (__bf16)vb[1][j],
                          (__bf16)vb[2][j], (__bf16)vb[3][j] };
            *(bf16x4*)bs_ptr[j] = b4;
        }
        __syncthreads();

        // prefetch next K-tile into registers (redundant reload of k_begin on last iter)
        int kn = (k0 + BK < k_end) ? (k0 + BK) : k_begin;
        va0 = *(const f32x4*)(aptr + kn);
        va1 = *(const f32x4*)(aptr + kn + 4);
#pragma unroll
        for (int i = 0; i < 4; ++i)
            vb[i] = *(const f32x4*)(bptr + (size_t)(kn + i) * H_DIM);

        // fragments + MFMA
        bf16x8 af[2], bfr[4];
#pragma unroll
        for (int mt = 0; mt < 2; ++mt)
            af[mt] = *(const bf16x8*)&As[((wm * 2 + mt) * 64 + lane) * 8];
#pragma unroll
        for (int nt = 0; nt < 4; ++nt)
            bfr[nt] = *(const bf16x8*)&Bs[((wn * 4 + nt) * 64 + lane) * 8];
#pragma unroll
        for (int mt = 0; mt < 2; ++mt)
#pragma unroll
            for (int nt = 0; nt < 4; ++nt)
                acc[mt][nt] = __builtin_amdgcn_mfma_f32_16x16x32_bf16(
                    af[mt], bfr[nt], acc[mt][nt], 0, 0, 0);
        __syncthreads();
    }

    // epilogue: C/D layout col=lane&15, row=(lane>>4)*4+reg
    float* sbase = scratch + (size_t)khalf * ROWS * H_DIM;
    const int lq = lane >> 4, ln = lane & 15;
#pragma unroll
    for (int mt = 0; mt < 2; ++mt) {
#pragma unroll
        for (int j = 0; j < 4; ++j) {
            int gm = m0 + wm * 32 + mt * 16 + lq * 4 + j;
            if (gm < cnt_e) {
                int row = rl[gm];
                float* orow = sbase + (size_t)row * H_DIM + n0 + wn * 64 + ln;
#pragma unroll
                for (int nt = 0; nt < 4; ++nt)
                    orow[nt * 16] = acc[mt][nt][j];
            }
        }
    }
}

// out[t] = w0*(s0[2t]+s1[2t]) + w1*(s0[2t+1]+s1[2t+1])
__global__ void reduce_kernel(const float* __restrict__ scratch,
                              const float* __restrict__ topk_w,
                              float* __restrict__ out) {
    int idx = blockIdx.x * blockDim.x + threadIdx.x;   // over T*H/4
    int t = idx >> 8;          // H/4 = 256 float4 per token
    int hq = idx & 255;
    float w0 = topk_w[2 * t];
    float w1 = topk_w[2 * t + 1];
    const f32x4* s = (const f32x4*)scratch;
    f32x4 a0 = s[(size_t)(2 * t) * 256 + hq];
    f32x4 a1 = s[(size_t)(2 * t + 1) * 256 + hq];
    f32x4 b0 = s[(size_t)ROWS * 256 + (size_t)(2 * t) * 256 + hq];
    f32x4 b1 = s[(size_t)ROWS * 256 + (size_t)(2 * t + 1) * 256 + hq];
    f32x4 r = (a0 + b0) * w0 + (a1 + b1) * w1;
    ((f32x4*)out)[idx] = r;
}

extern "C" void kernel_launch(void* const* d_in, const int* in_sizes, int n_in,
                              void* d_out, int out_size, void* d_ws, size_t ws_size,
                              hipStream_t stream) {
    const float* x      = (const float*)d_in[0];  // [ROWS, I_DIM] fp32
    const float* w      = (const float*)d_in[1];  // [E, I_DIM, H_DIM] fp32
    const float* logits = (const float*)d_in[2];  // [T, E] fp32
    float* out = (float*)d_out;                   // [T, H_DIM] fp32

    char* ws = (char*)d_ws;
    float* topk_w  = (float*)ws;                                  // 4096 f32
    int*   cnt     = (int*)(ws + 16384);                          // 8 int (padded)
    int*   rowlist = (int*)(ws + 16384 + 128);                    // 8*4096 int
    float* scratch = (float*)(ws + 16384 + 128 + 131072);         // 2*4096*1024 f32 (32 MB)

    hipMemsetAsync(cnt, 0, N_EXPERTS * sizeof(int), stream);
    routing_kernel<<<T_TOKENS / 256, 256, 0, stream>>>(logits, topk_w, cnt, rowlist);
    gemm_kernel<<<dim3(ROWS / M_TILE, (H_DIM / N_TILE) * KSPLIT, N_EXPERTS), 256, 0, stream>>>(
        x, w, cnt, rowlist, scratch);
    reduce_kernel<<<(T_TOKENS * H_DIM / 4) / 256, 256, 0, stream>>>(scratch, topk_w, out);
}

// Round 3
// 317.997 us; speedup vs baseline: 1.2941x; 1.0127x over previous
//
#include <hip/hip_runtime.h>

#define T_TOKENS 2048
#define N_EXPERTS 8
#define ROWS (T_TOKENS * 2)      // T * TOPK
#define I_DIM 2048
#define H_DIM 1024

#define M_TILE 64
#define N_TILE 128
#define BK 32
#define KSPLIT 2
#define KCHUNK (I_DIM / KSPLIT)  // 1024

typedef __bf16 bf16x8 __attribute__((ext_vector_type(8)));
typedef __bf16 bf16x4 __attribute__((ext_vector_type(4)));
typedef float f32x4 __attribute__((ext_vector_type(4)));

// One thread per token: softmax over 8 logits, top-2 (strict '>' keeps lower index
// first on ties, matching jax.lax.top_k), append rows to per-expert lists.
__global__ void routing_kernel(const float* __restrict__ logits,
                               float* __restrict__ topk_w,
                               int* __restrict__ cnt,
                               int* __restrict__ rowlist) {
    int t = blockIdx.x * blockDim.x + threadIdx.x;
    if (t >= T_TOKENS) return;
    float l[8];
#pragma unroll
    for (int e = 0; e < 8; ++e) l[e] = logits[t * 8 + e];
    float mx = l[0];
#pragma unroll
    for (int e = 1; e < 8; ++e) mx = fmaxf(mx, l[e]);
    float s = 0.f;
#pragma unroll
    for (int e = 0; e < 8; ++e) { l[e] = expf(l[e] - mx); s += l[e]; }
    float inv = 1.f / s;
    float v0 = -1.f, v1 = -1.f; int i0 = 0, i1 = 0;
#pragma unroll
    for (int e = 0; e < 8; ++e) {
        float p = l[e] * inv;
        if (p > v0)      { v1 = v0; i1 = i0; v0 = p; i0 = e; }
        else if (p > v1) { v1 = p; i1 = e; }
    }
    topk_w[2 * t]     = v0;
    topk_w[2 * t + 1] = v1;
    int p0 = atomicAdd(&cnt[i0], 1); rowlist[i0 * ROWS + p0] = 2 * t;
    int p1 = atomicAdd(&cnt[i1], 1); rowlist[i1 * ROWS + p1] = 2 * t + 1;
}

// Grouped expert GEMM, 64x128 tile, bf16 MFMA 16x16x32, fragment-ordered LDS.
// Grid: x = ntile + 8*khalf (16, all active), y = expert (8), z = m-tile (64,
// early-exit tail) -> active blocks form a dense linear-id prefix and spread
// across all 256 CUs (round-robin dispatch).
// Depth-2 register prefetch: loads for iter k issued during iter k-2.
__global__ __launch_bounds__(256, 4) void gemm_kernel(
    const float* __restrict__ x, const float* __restrict__ w,
    const int* __restrict__ cnt, const int* __restrict__ rowlist,
    float* __restrict__ scratch) {
    const int e = blockIdx.y;
    const int cnt_e = cnt[e];
    const int m0 = blockIdx.z * M_TILE;
    if (m0 >= cnt_e) return;
    const int ntile = blockIdx.x & 7;
    const int khalf = blockIdx.x >> 3;
    const int n0 = ntile * N_TILE;
    const int tid = threadIdx.x;
    const int lane = tid & 63;
    const int wave = tid >> 6;
    const int wm = wave & 1, wn = wave >> 1;

    // fragment-ordered: chunk(m,k) = (m>>4)*64 + (k>>3)*16 + (m&15); elem = chunk*8 + (k&7)
    __shared__ __bf16 As[M_TILE * BK];   // 4 KB
    __shared__ __bf16 Bs[N_TILE * BK];   // 8 KB

    const int* rl = rowlist + e * ROWS;

    // A: thread -> row tid>>2 (64 rows), k-offset (tid&3)*8; one b128 LDS store
    const int arow = tid >> 2;
    const int ak = (tid & 3) * 8;
    int gmA = m0 + arow;
    int gmc = gmA < cnt_e ? gmA : cnt_e - 1;   // clamped garbage rows dropped in epilogue
    const float* aptr = x + (size_t)rl[gmc] * I_DIM + ak;
    __bf16* as_ptr = &As[((arow >> 4) * 64 + (ak >> 3) * 16 + (arow & 15)) * 8];

    // B: thread -> n quad (tid&31)*4, k quad (tid>>5)*4; 4 float4 loads, 4 b64 stores
    const int bn = (tid & 31) * 4;
    const int bkq = (tid >> 5) * 4;
    const float* bptr = w + (size_t)e * (I_DIM * H_DIM) + (size_t)bkq * H_DIM + n0 + bn;
    __bf16* bs_ptr[4];
#pragma unroll
    for (int j = 0; j < 4; ++j) {
        int n = bn + j;
        bs_ptr[j] = &Bs[(((n >> 4) * 64 + (bkq >> 3) * 16 + (n & 15)) * 8) + (bkq & 7)];
    }

    f32x4 acc[2][4];
#pragma unroll
    for (int mt = 0; mt < 2; ++mt)
#pragma unroll
        for (int nt = 0; nt < 4; ++nt)
            acc[mt][nt] = (f32x4){0.f, 0.f, 0.f, 0.f};

    const int k_begin = khalf * KCHUNK;
    const int k_end = k_begin + KCHUNK;

    // depth-2 prologue: stage 0 <- k_begin, stage 1 <- k_begin+BK
    f32x4 va0[2], va1[2], vb[2][4];
#pragma unroll
    for (int st = 0; st < 2; ++st) {
        int kb = k_begin + st * BK;
        va0[st] = *(const f32x4*)(aptr + kb);
        va1[st] = *(const f32x4*)(aptr + kb + 4);
#pragma unroll
        for (int i = 0; i < 4; ++i)
            vb[st][i] = *(const f32x4*)(bptr + (size_t)(kb + i) * H_DIM);
    }

    int s = 0;
    for (int k0 = k_begin; k0 < k_end; k0 += BK, s ^= 1) {
        // convert & store stage s to LDS (waits only this stage's loads)
        bf16x8 a8 = { (__bf16)va0[s].x, (__bf16)va0[s].y, (__bf16)va0[s].z, (__bf16)va0[s].w,
                      (__bf16)va1[s].x, (__bf16)va1[s].y, (__bf16)va1[s].z, (__bf16)va1[s].w };
        *(bf16x8*)as_ptr = a8;
#pragma unroll
        for (int j = 0; j < 4; ++j) {
            bf16x4 b4 = { (__bf16)vb[s][0][j], (__bf16)vb[s][1][j],
                          (__bf16)vb[s][2][j], (__bf16)vb[s][3][j] };
            *(bf16x4*)bs_ptr[j] = b4;
        }
        __syncthreads();

        // refill stage s with k0 + 2*BK (dummy reload of k_begin past the end)
        int kn = (k0 + 2 * BK < k_end) ? (k0 + 2 * BK) : k_begin;
        va0[s] = *(const f32x4*)(aptr + kn);
        va1[s] = *(const f32x4*)(aptr + kn + 4);
#pragma unroll
        for (int i = 0; i < 4; ++i)
            vb[s][i] = *(const f32x4*)(bptr + (size_t)(kn + i) * H_DIM);

        // fragments + MFMA
        bf16x8 af[2], bfr[4];
#pragma unroll
        for (int mt = 0; mt < 2; ++mt)
            af[mt] = *(const bf16x8*)&As[((wm * 2 + mt) * 64 + lane) * 8];
#pragma unroll
        for (int nt = 0; nt < 4; ++nt)
            bfr[nt] = *(const bf16x8*)&Bs[((wn * 4 + nt) * 64 + lane) * 8];
#pragma unroll
        for (int mt = 0; mt < 2; ++mt)
#pragma unroll
            for (int nt = 0; nt < 4; ++nt)
                acc[mt][nt] = __builtin_amdgcn_mfma_f32_16x16x32_bf16(
                    af[mt], bfr[nt], acc[mt][nt], 0, 0, 0);
        __syncthreads();
    }

    // epilogue: C/D layout col=lane&15, row=(lane>>4)*4+reg
    float* sbase = scratch + (size_t)khalf * ROWS * H_DIM;
    const int lq = lane >> 4, ln = lane & 15;
#pragma unroll
    for (int mt = 0; mt < 2; ++mt) {
#pragma unroll
        for (int j = 0; j < 4; ++j) {
            int gm = m0 + wm * 32 + mt * 16 + lq * 4 + j;
            if (gm < cnt_e) {
                int row = rl[gm];
                float* orow = sbase + (size_t)row * H_DIM + n0 + wn * 64 + ln;
#pragma unroll
                for (int nt = 0; nt < 4; ++nt)
                    orow[nt * 16] = acc[mt][nt][j];
            }
        }
    }
}

// out[t] = w0*(s0[2t]+s1[2t]) + w1*(s0[2t+1]+s1[2t+1])
__global__ void reduce_kernel(const float* __restrict__ scratch,
                              const float* __restrict__ topk_w,
                              float* __restrict__ out) {
    int idx = blockIdx.x * blockDim.x + threadIdx.x;   // over T*H/4
    int t = idx >> 8;          // H/4 = 256 float4 per token
    int hq = idx & 255;
    float w0 = topk_w[2 * t];
    float w1 = topk_w[2 * t + 1];
    const f32x4* s = (const f32x4*)scratch;
    f32x4 a0 = s[(size_t)(2 * t) * 256 + hq];
    f32x4 a1 = s[(size_t)(2 * t + 1) * 256 + hq];
    f32x4 b0 = s[(size_t)ROWS * 256 + (size_t)(2 * t) * 256 + hq];
    f32x4 b1 = s[(size_t)ROWS * 256 + (size_t)(2 * t + 1) * 256 + hq];
    f32x4 r = (a0 + b0) * w0 + (a1 + b1) * w1;
    ((f32x4*)out)[idx] = r;
}

extern "C" void kernel_launch(void* const* d_in, const int* in_sizes, int n_in,
                              void* d_out, int out_size, void* d_ws, size_t ws_size,
                              hipStream_t stream) {
    const float* x      = (const float*)d_in[0];  // [ROWS, I_DIM] fp32
    const float* w      = (const float*)d_in[1];  // [E, I_DIM, H_DIM] fp32
    const float* logits = (const float*)d_in[2];  // [T, E] fp32
    float* out = (float*)d_out;                   // [T, H_DIM] fp32

    char* ws = (char*)d_ws;
    float* topk_w  = (float*)ws;                                  // 4096 f32
    int*   cnt     = (int*)(ws + 16384);                          // 8 int (padded)
    int*   rowlist = (int*)(ws + 16384 + 128);                    // 8*4096 int
    float* scratch = (float*)(ws + 16384 + 128 + 131072);         // 2*4096*1024 f32 (32 MB)

    hipMemsetAsync(cnt, 0, N_EXPERTS * sizeof(int), stream);
    routing_kernel<<<T_TOKENS / 256, 256, 0, stream>>>(logits, topk_w, cnt, rowlist);
    // x = ntile+khalf (all active), y = expert, z = m-tile (early-exit tail)
    gemm_kernel<<<dim3((H_DIM / N_TILE) * KSPLIT, N_EXPERTS, ROWS / M_TILE), 256, 0, stream>>>(
        x, w, cnt, rowlist, scratch);
    reduce_kernel<<<(T_TOKENS * H_DIM / 4) / 256, 256, 0, stream>>>(scratch, topk_w, out);
}

// Round 4
// 215.975 us; speedup vs baseline: 1.9054x; 1.4724x over previous
//
#include <hip/hip_runtime.h>

#define T_TOKENS 2048
#define N_EXPERTS 8
#define ROWS (T_TOKENS * 2)      // T * TOPK
#define I_DIM 2048
#define H_DIM 1024

#define M_TILE 64
#define N_TILE 128
#define BK 32
#define KSPLIT 2
#define KCHUNK (I_DIM / KSPLIT)  // 1024

typedef __bf16 bf16x8 __attribute__((ext_vector_type(8)));
typedef __bf16 bf16x4 __attribute__((ext_vector_type(4)));
typedef float f32x4 __attribute__((ext_vector_type(4)));

__device__ inline void load_lds16(const void* g, void* l) {
    // lane i's 16B land at (wave-uniform) l + i*16
    __builtin_amdgcn_global_load_lds(
        (const __attribute__((address_space(1))) void*)g,
        (__attribute__((address_space(3))) void*)l, 16, 0, 0);
}

// Fused prep: (a) transpose+convert w [E][K][N] fp32 -> wT [E][N][K] bf16,
// (b) zero d_out, (c) zero cnt. One dispatch, stream-ordered before routing.
__global__ __launch_bounds__(256) void prep_kernel(
    const float* __restrict__ w, __bf16* __restrict__ wT,
    float* __restrict__ out, int* __restrict__ cnt) {
    const int bx = blockIdx.x;
    const int t = threadIdx.x;
    if (bx >= 4096) {
        // zero out: 1024 blocks * 256 thr * 8 floats = 2M floats
        int idx = (bx - 4096) * 256 + t;
        f32x4 z = (f32x4){0.f, 0.f, 0.f, 0.f};
        ((f32x4*)out)[2 * idx] = z;
        ((f32x4*)out)[2 * idx + 1] = z;
        if (bx == 4096 && t < N_EXPERTS) cnt[t] = 0;
        return;
    }
    // transpose 64(k) x 64(n) fp32 tile -> bf16 [n][k]
    __shared__ float tile[64 * 66];  // pitch 66 breaks bank conflicts
    const int e = bx >> 9;           // 512 blocks/expert = 32 ktiles * 16 ntiles
    const int k0 = ((bx >> 4) & 31) * 64;
    const int n0 = (bx & 15) * 64;
    const float* wsrc = w + (size_t)e * (I_DIM * H_DIM);
#pragma unroll
    for (int r = 0; r < 4; ++r) {
        int kl = (t >> 4) * 4 + r;
        int nl = (t & 15) * 4;
        f32x4 v = *(const f32x4*)(wsrc + (size_t)(k0 + kl) * H_DIM + n0 + nl);
        tile[kl * 66 + nl]     = v.x;
        tile[kl * 66 + nl + 1] = v.y;
        tile[kl * 66 + nl + 2] = v.z;
        tile[kl * 66 + nl + 3] = v.w;
    }
    __syncthreads();
    __bf16* wdst = wT + (size_t)e * (H_DIM * I_DIM);
#pragma unroll
    for (int r = 0; r < 4; ++r) {
        int nl = (t >> 4) * 4 + r;
        int klc = (t & 15) * 4;
        bf16x4 b = { (__bf16)tile[klc * 66 + nl],
                     (__bf16)tile[(klc + 1) * 66 + nl],
                     (__bf16)tile[(klc + 2) * 66 + nl],
                     (__bf16)tile[(klc + 3) * 66 + nl] };
        *(bf16x4*)(wdst + (size_t)(n0 + nl) * I_DIM + k0 + klc) = b;
    }
}

// One thread per token: softmax over 8 logits, top-2 (strict '>' keeps lower index
// first on ties, matching jax.lax.top_k), append rows to per-expert lists.
__global__ void routing_kernel(const float* __restrict__ logits,
                               float* __restrict__ topk_w,
                               int* __restrict__ cnt,
                               int* __restrict__ rowlist) {
    int t = blockIdx.x * blockDim.x + threadIdx.x;
    if (t >= T_TOKENS) return;
    float l[8];
#pragma unroll
    for (int e = 0; e < 8; ++e) l[e] = logits[t * 8 + e];
    float mx = l[0];
#pragma unroll
    for (int e = 1; e < 8; ++e) mx = fmaxf(mx, l[e]);
    float s = 0.f;
#pragma unroll
    for (int e = 0; e < 8; ++e) { l[e] = expf(l[e] - mx); s += l[e]; }
    float inv = 1.f / s;
    float v0 = -1.f, v1 = -1.f; int i0 = 0, i1 = 0;
#pragma unroll
    for (int e = 0; e < 8; ++e) {
        float p = l[e] * inv;
        if (p > v0)      { v1 = v0; i1 = i0; v0 = p; i0 = e; }
        else if (p > v1) { v1 = p; i1 = e; }
    }
    topk_w[2 * t]     = v0;
    topk_w[2 * t + 1] = v1;
    int p0 = atomicAdd(&cnt[i0], 1); rowlist[i0 * ROWS + p0] = 2 * t;
    int p1 = atomicAdd(&cnt[i1], 1); rowlist[i1 * ROWS + p1] = 2 * t + 1;
}

// Grouped expert GEMM, 64x128 tile, bf16 MFMA 16x16x32.
// B (wT, bf16) staged via global_load_lds DMA (no VGPR round-trip).
// A (x, fp32, rowlist-gathered) via depth-1 register prefetch (8 VGPRs) + cvt.
// Epilogue: scale by topk weight and atomicAdd directly into out.
__global__ __launch_bounds__(256, 4) void gemm_kernel(
    const float* __restrict__ x, const __bf16* __restrict__ wT,
    const int* __restrict__ cnt, const int* __restrict__ rowlist,
    const float* __restrict__ topk_w, float* __restrict__ out) {
    const int e = blockIdx.y;
    const int cnt_e = cnt[e];
    const int m0 = blockIdx.z * M_TILE;
    if (m0 >= cnt_e) return;
    const int ntile = blockIdx.x & 7;
    const int khalf = blockIdx.x >> 3;
    const int n0 = ntile * N_TILE;
    const int tid = threadIdx.x;
    const int lane = tid & 63;
    const int wave = tid >> 6;
    const int wm = wave & 1, wn = wave >> 1;

    // row-major LDS tiles: A [64 rows][32 bf16] (64 B/row), B [128 n-rows][32 bf16]
    __shared__ __bf16 As[M_TILE * BK];   // 4 KB
    __shared__ __bf16 Bs[N_TILE * BK];   // 8 KB

    const int* rl = rowlist + e * ROWS;

    // A: wave stages rows [16*wave, +16): lane -> row 16w + (l>>2), chunk (l&3)*8 f32
    const int arow = 16 * wave + (lane >> 2);
    int gmA = m0 + arow;
    int gmc = gmA < cnt_e ? gmA : cnt_e - 1;   // clamped garbage dropped in epilogue
    const float* aptr = x + (size_t)rl[gmc] * I_DIM + (lane & 3) * 8;
    __bf16* as_dst = &As[wave * 512];          // uniform per wave; lane lands at +l*16B
    __bf16* as_wr  = &As[arow * 32 + (lane & 3) * 8];

    // B: wave stages n-rows [32*wave, +32) in 2 DMA instrs of 16 rows
    const __bf16* wTe = wT + (size_t)e * (H_DIM * I_DIM);
    const __bf16* bgp0 = wTe + (size_t)(n0 + 32 * wave + (lane >> 2)) * I_DIM + (lane & 3) * 8;
    const __bf16* bgp1 = bgp0 + 16 * I_DIM;
    __bf16* bs_dst0 = &Bs[wave * 1024];        // rows 32w..32w+15
    __bf16* bs_dst1 = &Bs[wave * 1024 + 512];  // rows 32w+16..32w+31

    f32x4 acc[2][4];
#pragma unroll
    for (int mt = 0; mt < 2; ++mt)
#pragma unroll
        for (int nt = 0; nt < 4; ++nt)
            acc[mt][nt] = (f32x4){0.f, 0.f, 0.f, 0.f};

    const int k_begin = khalf * KCHUNK;
    const int k_end = k_begin + KCHUNK;

    // depth-1 A prologue
    f32x4 va0 = *(const f32x4*)(aptr + k_begin);
    f32x4 va1 = *(const f32x4*)(aptr + k_begin + 4);

    for (int k0 = k_begin; k0 < k_end; k0 += BK) {
        __syncthreads();   // LDS safe to overwrite
        // B tile k0: fire-and-forget DMA to LDS
        load_lds16(bgp0 + k0, bs_dst0);
        load_lds16(bgp1 + k0, bs_dst1);
        // A tile k0: cvt prefetched regs -> LDS
        bf16x8 a8 = { (__bf16)va0.x, (__bf16)va0.y, (__bf16)va0.z, (__bf16)va0.w,
                      (__bf16)va1.x, (__bf16)va1.y, (__bf16)va1.z, (__bf16)va1.w };
        *(bf16x8*)as_wr = a8;
        __syncthreads();   // drains DMA + ds_write

        // prefetch next A during MFMA phase (dummy k_begin reload on last iter)
        int kn = (k0 + BK < k_end) ? (k0 + BK) : k_begin;
        va0 = *(const f32x4*)(aptr + kn);
        va1 = *(const f32x4*)(aptr + kn + 4);

        bf16x8 af[2], bfr[4];
#pragma unroll
        for (int mt = 0; mt < 2; ++mt)
            af[mt] = *(const bf16x8*)&As[(wm * 32 + mt * 16 + (lane & 15)) * 32 + (lane >> 4) * 8];
#pragma unroll
        for (int nt = 0; nt < 4; ++nt)
            bfr[nt] = *(const bf16x8*)&Bs[(wn * 64 + nt * 16 + (lane & 15)) * 32 + (lane >> 4) * 8];
#pragma unroll
        for (int mt = 0; mt < 2; ++mt)
#pragma unroll
            for (int nt = 0; nt < 4; ++nt)
                acc[mt][nt] = __builtin_amdgcn_mfma_f32_16x16x32_bf16(
                    af[mt], bfr[nt], acc[mt][nt], 0, 0, 0);
    }

    // epilogue: C/D col=lane&15, row=(lane>>4)*4+reg; scale by topk weight,
    // atomicAdd into out[token] (covers topk-sum and K-split sum)
    const int lq = lane >> 4, ln = lane & 15;
#pragma unroll
    for (int mt = 0; mt < 2; ++mt) {
#pragma unroll
        for (int j = 0; j < 4; ++j) {
            int gm = m0 + wm * 32 + mt * 16 + lq * 4 + j;
            if (gm < cnt_e) {
                int row = rl[gm];
                float tw = topk_w[row];
                float* orow = out + (size_t)(row >> 1) * H_DIM + n0 + wn * 64 + ln;
#pragma unroll
                for (int nt = 0; nt < 4; ++nt)
                    atomicAdd(&orow[nt * 16], acc[mt][nt][j] * tw);
            }
        }
    }
}

extern "C" void kernel_launch(void* const* d_in, const int* in_sizes, int n_in,
                              void* d_out, int out_size, void* d_ws, size_t ws_size,
                              hipStream_t stream) {
    const float* x      = (const float*)d_in[0];  // [ROWS, I_DIM] fp32
    const float* w      = (const float*)d_in[1];  // [E, I_DIM, H_DIM] fp32
    const float* logits = (const float*)d_in[2];  // [T, E] fp32
    float* out = (float*)d_out;                   // [T, H_DIM] fp32

    char* ws = (char*)d_ws;
    float*  topk_w  = (float*)ws;                           // 4096 f32 (16 KB)
    int*    cnt     = (int*)(ws + 16384);                   // 8 int (padded)
    int*    rowlist = (int*)(ws + 16384 + 128);             // 8*4096 int (128 KB)
    __bf16* wT      = (__bf16*)(ws + 16384 + 128 + 131072); // [E][H][I] bf16 (32 MB)

    // prep: w transpose+convert (4096 blocks) + out zero (1024) + cnt zero
    prep_kernel<<<4096 + 1024, 256, 0, stream>>>(w, wT, out, cnt);
    routing_kernel<<<T_TOKENS / 256, 256, 0, stream>>>(logits, topk_w, cnt, rowlist);
    // x = ntile+khalf (all active), y = expert, z = m-tile (early-exit tail)
    gemm_kernel<<<dim3((H_DIM / N_TILE) * KSPLIT, N_EXPERTS, ROWS / M_TILE), 256, 0, stream>>>(
        x, wT, cnt, rowlist, topk_w, out);
}